// Round 6
// baseline (468.572 us; speedup 1.0000x reference)
//
#include <hip/hip_runtime.h>

// Correlation / cost-volume, fp32.
// corr[b, dy*9+dx, y, x] = (1/128) * sum_c in1[b,c,y,x] * in2[b,c,y+dy-4,x+dx-4]
//
// R13: TLP restructure. R12 evidence: VALUBusy 36.8% ~= issued/duration,
// occupancy 11.3% (~0.9 waves/SIMD effective), hbm 13.7% -> issue-starved,
// TLP-bound; depth-4 pipeline can't help a lone wave (wall ~2000 cyc/chunk
// vs 190 cyc own issue). Fix: NT 320->576 (9 waves, ZERO idle lanes:
// 4ly x 9dy x 16xg = 576), TY 2->4, grid 512->256 blocks = 1/CU perfectly
// balanced. Per-thread work identical to R12 (acc[9][8], DPP x-halos,
// depth-4 register pipeline, no LDS, no barriers). 9 free-running waves/CU
// overlap stalls. Floors: VALU ~23 us, L1-BW ~31 us. Target 40-60 us.

#define MAXD 4
#define ND 9
#define NDISP 81
#define BATCH 8
#define CH 128
#define HH 128
#define WW 128
#define HW (HH * WW)
#define NCHUNK CH                 // 1 channel per pipeline stage
#define TY 4
#define NT 576                    // 9 waves; every lane computes

__device__ __forceinline__ float dpp_shr1(float x) {   // lane i <- lane i-1 (row16)
    return __int_as_float(__builtin_amdgcn_update_dpp(
        0, __float_as_int(x), 0x111, 0xF, 0xF, true));
}
__device__ __forceinline__ float dpp_shl1(float x) {   // lane i <- lane i+1 (row16)
    return __int_as_float(__builtin_amdgcn_update_dpp(
        0, __float_as_int(x), 0x101, 0xF, 0xF, true));
}

__global__ __launch_bounds__(NT, 2) void corr_kernel(
    const float* __restrict__ in1,
    const float* __restrict__ in2,
    float* __restrict__ out)
{
    const int tid = threadIdx.x;
    const int b   = blockIdx.x;
    const int y0  = blockIdx.y * TY;
    const int xg  = tid & 15;               // 16 lanes span the 128-px row
    const int dy  = (tid >> 4) % ND;        // 9 dy groups
    const int ly  = tid / 144;              // 0..3: row within tile
    const int rl  = ly + dy;                // in2 row offset consumed (0..11)
    const bool rok = (unsigned)(y0 + rl - MAXD) < (unsigned)HH;
    int r2 = y0 + rl - MAXD;                // clamped row; garbage zeroed at end
    r2 = r2 < 0 ? 0 : (r2 > HH - 1 ? HH - 1 : r2);

    const float* p2 = in2 + (size_t)b * CH * HW + (size_t)r2 * WW + xg * 8;
    const float* p1 = in1 + (size_t)b * CH * HW + (size_t)(y0 + ly) * WW + xg * 8;

    float acc[ND][8];
    #pragma unroll
    for (int d = 0; d < ND; ++d)
        #pragma unroll
        for (int i = 0; i < 8; ++i) acc[d][i] = 0.0f;

    // 4 named pipeline stages (static indexing only -> registers, rule #20)
    float w0[8], a0[8], w1[8], a1[8], w2[8], a2[8], w3[8], a3[8];

    // load current chunk's 32B of in2 (w) and 32B of in1 (a); advance ptrs
    auto LD = [&](float* w, float* a) {
        float4 t0 = *(const float4*)(p2);
        float4 t1 = *(const float4*)(p2 + 4);
        float4 u0 = *(const float4*)(p1);
        float4 u1 = *(const float4*)(p1 + 4);
        w[0] = t0.x; w[1] = t0.y; w[2] = t0.z; w[3] = t0.w;
        w[4] = t1.x; w[5] = t1.y; w[6] = t1.z; w[7] = t1.w;
        a[0] = u0.x; a[1] = u0.y; a[2] = u0.z; a[3] = u0.w;
        a[4] = u1.x; a[5] = u1.y; a[6] = u1.z; a[7] = u1.w;
        p2 += HW; p1 += HW;
    };

    auto CMP = [&](const float* w, const float* a) {
        float W[16];
        W[0]  = dpp_shr1(w[4]);   // x-4..x-1 from lane-1; 0 at image edge
        W[1]  = dpp_shr1(w[5]);
        W[2]  = dpp_shr1(w[6]);
        W[3]  = dpp_shr1(w[7]);
        #pragma unroll
        for (int i = 0; i < 8; ++i) W[4 + i] = w[i];
        W[12] = dpp_shl1(w[0]);   // x+8..x+11 from lane+1; 0 at image edge
        W[13] = dpp_shl1(w[1]);
        W[14] = dpp_shl1(w[2]);
        W[15] = dpp_shl1(w[3]);
        #pragma unroll
        for (int d = 0; d < ND; ++d)
            #pragma unroll
            for (int i = 0; i < 8; ++i)
                acc[d][i] = fmaf(a[i], W[i + d], acc[d][i]);
    };

    // ---- depth-4 software pipeline: 4 chunks per iteration ----
    LD(w0, a0);                   // chunk 0
    LD(w1, a1);                   // chunk 1
    LD(w2, a2);                   // chunk 2
    #pragma unroll 1
    for (int k = 0; k <= NCHUNK - 8; k += 4) {   // k = 0,4,...,120
        LD(w3, a3);  CMP(w0, a0); // load k+3, compute k
        LD(w0, a0);  CMP(w1, a1); // load k+4, compute k+1
        LD(w1, a1);  CMP(w2, a2); // load k+5, compute k+2
        LD(w2, a2);  CMP(w3, a3); // load k+6, compute k+3
    }
    // tail (k=124): stages hold 124,125,126; one last in-bounds load of 127
    LD(w3, a3);
    CMP(w0, a0); CMP(w1, a1); CMP(w2, a2); CMP(w3, a3);

    // ---- epilogue: mean over C; OOB rows scale to exact zero ----
    const float sc = rok ? (1.0f / (float)CH) : 0.0f;
    float* outb = out + (size_t)b * NDISP * HW
                      + (size_t)(y0 + ly) * WW + xg * 8;
    #pragma unroll
    for (int d = 0; d < ND; ++d) {
        float* op = outb + (size_t)(dy * ND + d) * HW;
        float4 v0 = make_float4(acc[d][0] * sc, acc[d][1] * sc,
                                acc[d][2] * sc, acc[d][3] * sc);
        float4 v1 = make_float4(acc[d][4] * sc, acc[d][5] * sc,
                                acc[d][6] * sc, acc[d][7] * sc);
        *(float4*)(op)     = v0;
        *(float4*)(op + 4) = v1;
    }
}

extern "C" void kernel_launch(void* const* d_in, const int* in_sizes, int n_in,
                              void* d_out, int out_size, void* d_ws, size_t ws_size,
                              hipStream_t stream) {
    const float* in1 = (const float*)d_in[0];
    const float* in2 = (const float*)d_in[1];
    float* out = (float*)d_out;
    dim3 grid(BATCH, HH / TY);
    corr_kernel<<<grid, NT, 0, stream>>>(in1, in2, out);
}

// Round 10
// 188.333 us; speedup vs baseline: 2.4880x; 2.4880x over previous
//
#include <hip/hip_runtime.h>

// Correlation / cost-volume, fp32.
// corr[b, dy*9+dx, y, x] = (1/128) * sum_c in1[b,c,y,x] * in2[b,c,y+dy-4,x+dx-4]
//
// R17 = R14 resubmitted verbatim (broker timeouts R7/R8/R9; acquisition
// fails pre-launch => no kernel evidence; theory unfalsified, audited 3x).
// R14: fix R13's spill. R13 evidence: VGPR 84 (capped), WRITE_SIZE 796 MB
// (19x = acc[72] scratch spill), VALUBusy 9.8%. Root cause: R13 kept
// __launch_bounds__(576,2) => 18 waves/CU => unified cap ~112/wave.
// Fix: depth-2 pipeline (R10 measured 76 arch + 72 acc = 148) +
// __launch_bounds__(576,1) => cap 170, headroom 22. Keeps R13's
// zero-dead-lane geometry: NT=576 (4ly x 9dy x 16xg bijective), TY=4,
// grid 256 = 1 block/CU, 9 waves/CU.
// Pacing s_barrier (raw asm, no waitcnt, no memory clobber) every 2
// chunks -- semantically free (uniform control flow, no early exit,
// threads self-sufficient => no hang, no drain), keeps the block's 9
// waves chunk-aligned so the 4.6x read redundancy (36.9 KB issued vs
// 8 KB unique rows/chunk) hits L1 instead of re-pulling L2/L3. R12's
// 108 us matched a ~11 TB/s vector-traffic ceiling (1.21 GB / 108 us)
// => cut effective traffic via time-alignment, not LDS.

#define MAXD 4
#define ND 9
#define NDISP 81
#define BATCH 8
#define CH 128
#define HH 128
#define WW 128
#define HW (HH * WW)
#define NCHUNK CH                 // 1 channel per pipeline stage
#define TY 4
#define NT 576                    // 9 waves; every lane computes

__device__ __forceinline__ float dpp_shr1(float x) {   // lane i <- lane i-1 (row16)
    return __int_as_float(__builtin_amdgcn_update_dpp(
        0, __float_as_int(x), 0x111, 0xF, 0xF, true));
}
__device__ __forceinline__ float dpp_shl1(float x) {   // lane i <- lane i+1 (row16)
    return __int_as_float(__builtin_amdgcn_update_dpp(
        0, __float_as_int(x), 0x101, 0xF, 0xF, true));
}

__global__ __launch_bounds__(NT, 1) void corr_kernel(
    const float* __restrict__ in1,
    const float* __restrict__ in2,
    float* __restrict__ out)
{
    const int tid = threadIdx.x;
    const int b   = blockIdx.x;
    const int y0  = blockIdx.y * TY;
    const int xg  = tid & 15;               // 16 lanes span the 128-px row
    const int dy  = (tid >> 4) % ND;        // 9 dy groups
    const int ly  = tid / 144;              // 0..3: row within tile
    const int rl  = ly + dy;                // in2 row offset consumed (0..11)
    const bool rok = (unsigned)(y0 + rl - MAXD) < (unsigned)HH;
    int r2 = y0 + rl - MAXD;                // clamped row; garbage zeroed at end
    r2 = r2 < 0 ? 0 : (r2 > HH - 1 ? HH - 1 : r2);

    const float* p2 = in2 + (size_t)b * CH * HW + (size_t)r2 * WW + xg * 8;
    const float* p1 = in1 + (size_t)b * CH * HW + (size_t)(y0 + ly) * WW + xg * 8;

    float acc[ND][8];
    #pragma unroll
    for (int d = 0; d < ND; ++d)
        #pragma unroll
        for (int i = 0; i < 8; ++i) acc[d][i] = 0.0f;

    // 2 named pipeline stages (static indexing only -> registers, rule #20)
    float w0[8], a0[8], w1[8], a1[8];

    // load current chunk's 32B of in2 (w) and 32B of in1 (a); advance ptrs
    auto LD = [&](float* w, float* a) {
        float4 t0 = *(const float4*)(p2);
        float4 t1 = *(const float4*)(p2 + 4);
        float4 u0 = *(const float4*)(p1);
        float4 u1 = *(const float4*)(p1 + 4);
        w[0] = t0.x; w[1] = t0.y; w[2] = t0.z; w[3] = t0.w;
        w[4] = t1.x; w[5] = t1.y; w[6] = t1.z; w[7] = t1.w;
        a[0] = u0.x; a[1] = u0.y; a[2] = u0.z; a[3] = u0.w;
        a[4] = u1.x; a[5] = u1.y; a[6] = u1.z; a[7] = u1.w;
        p2 += HW; p1 += HW;
    };

    auto CMP = [&](const float* w, const float* a) {
        float W[16];
        W[0]  = dpp_shr1(w[4]);   // x-4..x-1 from lane-1; 0 at image edge
        W[1]  = dpp_shr1(w[5]);
        W[2]  = dpp_shr1(w[6]);
        W[3]  = dpp_shr1(w[7]);
        #pragma unroll
        for (int i = 0; i < 8; ++i) W[4 + i] = w[i];
        W[12] = dpp_shl1(w[0]);   // x+8..x+11 from lane+1; 0 at image edge
        W[13] = dpp_shl1(w[1]);
        W[14] = dpp_shl1(w[2]);
        W[15] = dpp_shl1(w[3]);
        #pragma unroll
        for (int d = 0; d < ND; ++d)
            #pragma unroll
            for (int i = 0; i < 8; ++i)
                acc[d][i] = fmaf(a[i], W[i + d], acc[d][i]);
    };

    // ---- depth-2 software pipeline, pacing barrier every 2 chunks ----
    LD(w0, a0);                               // chunk 0
    #pragma unroll 1
    for (int k = 0; k < NCHUNK; k += 2) {
        LD(w1, a1);                           // chunk k+1
        CMP(w0, a0);                          // chunk k
        if (k + 2 < NCHUNK) LD(w0, a0);       // chunk k+2
        CMP(w1, a1);                          // chunk k+1
        // pacing only: no waitcnt, no memory clobber, uniform control flow.
        // Correctness does not depend on it (threads are self-sufficient);
        // it keeps the block's 9 waves chunk-aligned so redundant row reads
        // (4.6x) hit L1 instead of re-fetching from L2/L3.
        asm volatile("s_barrier");
    }

    // ---- epilogue: mean over C; OOB rows scale to exact zero ----
    const float sc = rok ? (1.0f / (float)CH) : 0.0f;
    float* outb = out + (size_t)b * NDISP * HW
                      + (size_t)(y0 + ly) * WW + xg * 8;
    #pragma unroll
    for (int d = 0; d < ND; ++d) {
        float* op = outb + (size_t)(dy * ND + d) * HW;
        float4 v0 = make_float4(acc[d][0] * sc, acc[d][1] * sc,
                                acc[d][2] * sc, acc[d][3] * sc);
        float4 v1 = make_float4(acc[d][4] * sc, acc[d][5] * sc,
                                acc[d][6] * sc, acc[d][7] * sc);
        *(float4*)(op)     = v0;
        *(float4*)(op + 4) = v1;
    }
}

extern "C" void kernel_launch(void* const* d_in, const int* in_sizes, int n_in,
                              void* d_out, int out_size, void* d_ws, size_t ws_size,
                              hipStream_t stream) {
    const float* in1 = (const float*)d_in[0];
    const float* in2 = (const float*)d_in[1];
    float* out = (float*)d_out;
    dim3 grid(BATCH, HH / TY);
    corr_kernel<<<grid, NT, 0, stream>>>(in1, in2, out);
}